// Round 4
// baseline (333.038 us; speedup 1.0000x reference)
//
#include <hip/hip_runtime.h>
#include <stdint.h>

#define LOG2E  1.44269504088896f
#define QSCALE (0.125f * LOG2E)   // folded into Q: sacc is already the exp2 argument

typedef float    f32x4_t  __attribute__((ext_vector_type(4)));
typedef float    f32x16_t __attribute__((ext_vector_type(16)));
typedef _Float16 f16x8_t  __attribute__((ext_vector_type(8)));
typedef _Float16 f16x2_t  __attribute__((ext_vector_type(2)));

#if __has_builtin(__builtin_amdgcn_exp2f)
#define EXP2F(x) __builtin_amdgcn_exp2f(x)
#else
#define EXP2F(x) exp2f(x)
#endif

__device__ __forceinline__ float rowsum2(f16x2_t p, float acc) {
#if __has_builtin(__builtin_amdgcn_fdot2)
  return __builtin_amdgcn_fdot2(p, (f16x2_t){(_Float16)1.0f, (_Float16)1.0f}, acc, false);
#else
  return acc + (float)p[0] + (float)p[1];
#endif
}

// ---------------- mask all-zero scan ----------------
__global__ void mask_scan_kernel(const float* __restrict__ m, int* __restrict__ flag) {
  const float* p = m + (size_t)blockIdx.x * 8192 + (size_t)threadIdx.x * 4;
  unsigned acc = 0;
#pragma unroll
  for (int i = 0; i < 8; ++i) {
    f32x4_t v = *(const f32x4_t*)(p + (size_t)i * 1024);
    acc |= __float_as_uint(v[0]) | __float_as_uint(v[1]) |
           __float_as_uint(v[2]) | __float_as_uint(v[3]);
  }
  acc &= 0x7fffffffu;
  if (acc) atomicOr(flag, 1);
}

// ---------------- pre-convert Q (scaled) and K to fp16 ----------------
__global__ void convert_qk_kernel(const float* __restrict__ Q, const float* __restrict__ K,
                                  _Float16* __restrict__ Qh, _Float16* __restrict__ Kh) {
  const size_t idx = ((size_t)blockIdx.x * 256 + threadIdx.x) * 8;
  {
    f32x4_t a = *(const f32x4_t*)(Q + idx);
    f32x4_t b = *(const f32x4_t*)(Q + idx + 4);
    union { _Float16 h[8]; uint4 q; } U;
#pragma unroll
    for (int j = 0; j < 4; ++j) { U.h[j] = (_Float16)(a[j] * QSCALE); U.h[4 + j] = (_Float16)(b[j] * QSCALE); }
    *(uint4*)(Qh + idx) = U.q;
  }
  {
    f32x4_t a = *(const f32x4_t*)(K + idx);
    f32x4_t b = *(const f32x4_t*)(K + idx + 4);
    union { _Float16 h[8]; uint4 q; } U;
#pragma unroll
    for (int j = 0; j < 4; ++j) { U.h[j] = (_Float16)a[j]; U.h[4 + j] = (_Float16)b[j]; }
    *(uint4*)(Kh + idx) = U.q;
  }
}

// ---------------- pre-transpose V to fp16 [head][feat][seq] ----------------
__global__ void transpose_v_kernel(const float* __restrict__ V, _Float16* __restrict__ Vth) {
  __shared__ __align__(16) _Float16 T[64 * 72];
  const int tid  = threadIdx.x;
  const int head = blockIdx.x >> 6;
  const int st   = blockIdx.x & 63;
  const size_t hoff = (size_t)head * 4096 * 64;

  const int sl    = tid >> 2;
  const int fbase = (tid & 3) * 16;
  const float* src = V + hoff + (size_t)(st * 64 + sl) * 64 + fbase;
#pragma unroll
  for (int c = 0; c < 4; ++c) {
    f32x4_t a = *(const f32x4_t*)(src + c * 4);
#pragma unroll
    for (int j = 0; j < 4; ++j) T[(fbase + c * 4 + j) * 72 + sl] = (_Float16)a[j];
  }
  __syncthreads();
  const int feat = tid >> 2;
  const int sb   = (tid & 3) * 16;
  uint4 r0 = *(const uint4*)&T[feat * 72 + sb];
  uint4 r1 = *(const uint4*)&T[feat * 72 + sb + 8];
  _Float16* dst = Vth + hoff + (size_t)feat * 4096 + st * 64 + sb;
  *(uint4*)(dst)     = r0;
  *(uint4*)(dst + 8) = r1;
}

// ---------------- SDPA core v2: 128 threads (2 waves), 64 q/wave, 128 q/block ----
// sigma trick: reading K rows through sig(n)=swap(bit2,bit3 of n) during S^T=K.Q^T
// relabels C-rows so PV A-fragments are lane-local sacc regs (no P LDS round-trip).
// K/V LDS fragments are reused across both q-halves -> 0.5 LDS reads per MFMA.
__launch_bounds__(128, 2)
__global__ void sdpa_kernel2(const _Float16* __restrict__ Qh, const _Float16* __restrict__ Kh,
                             const _Float16* __restrict__ Vth, const float* __restrict__ Mg,
                             float* __restrict__ Og, const int* __restrict__ flag) {
  __shared__ __align__(16) _Float16 Ks[64 * 72];   // [key][feat], stride 72 (conflict-free, measured)
  __shared__ __align__(16) _Float16 Vt[64 * 72];   // [feat][key]

  const int t    = threadIdx.x;
  const int bid  = blockIdx.x;                           // 0..511
  const int hh   = ((bid & 7) << 1) | ((bid >> 3) & 1);  // 2 heads per XCD
  const int qt   = bid >> 4;                             // 0..31
  const int w    = t >> 6;
  const int lane = t & 63;
  const int n    = lane & 31;
  const int h2   = lane >> 5;
  const int sig  = (n & 0x13) | ((n >> 1) & 4) | ((n << 1) & 8);  // swap bits 2,3
  const bool has_mask = (*flag) != 0;

  const size_t hoff = (size_t)hh * 4096 * 64;
  const int qb = qt * 128 + w * 64;                      // wave's q base (64 q)

  // ---- Q B-fragments for both q-halves: lane holds Q[q][kh*16 + 8*h2 + j] ----
  f16x8_t qf[2][4];
#pragma unroll
  for (int qh = 0; qh < 2; ++qh) {
    const _Float16* qp = Qh + hoff + (size_t)(qb + qh * 32 + n) * 64 + 8 * h2;
#pragma unroll
    for (int kh = 0; kh < 4; ++kh) qf[qh][kh] = *(const f16x8_t*)(qp + kh * 16);
  }

  f32x16_t o00 = {0.f,0.f,0.f,0.f,0.f,0.f,0.f,0.f,0.f,0.f,0.f,0.f,0.f,0.f,0.f,0.f};
  f32x16_t o01 = o00, o10 = o00, o11 = o00;   // o[qh][colhalf]
  float lacc0 = 0.0f, lacc1 = 0.0f;

  // staging: thread t handles K row t>>1 (feat half t&1) and Vth feat t>>1 (seq half t&1)
  const int sr = t >> 1;
  const int sh = (t & 1) * 32;
  const _Float16* kbase_p = Kh  + hoff + (size_t)sr * 64 + sh;
  const _Float16* vbase_p = Vth + hoff + (size_t)sr * 4096 + sh;

  uint4 kk[4], vv[4];
#pragma unroll
  for (int j = 0; j < 4; ++j) {               // prefetch kt=0
    kk[j] = ((const uint4*)kbase_p)[j];
    vv[j] = ((const uint4*)vbase_p)[j];
  }

#pragma unroll 1
  for (int kt = 0; kt < 64; ++kt) {
    const int kbase = kt * 64;

    __syncthreads();   // prior iteration's LDS reads complete before overwrite
    {
      uint4* kd = (uint4*)&Ks[sr * 72 + sh];
      uint4* vd = (uint4*)&Vt[sr * 72 + sh];
#pragma unroll
      for (int j = 0; j < 4; ++j) { kd[j] = kk[j]; vd[j] = vv[j]; }
    }
    __syncthreads();   // staging visible to both waves

    if (kt < 63) {     // software pipeline: issue next tile's loads; latency hides under compute
      const _Float16* kp = kbase_p + (size_t)(kbase + 64) * 64;
      const _Float16* vp = vbase_p + (kbase + 64);
#pragma unroll
      for (int j = 0; j < 4; ++j) {
        kk[j] = ((const uint4*)kp)[j];
        vv[j] = ((const uint4*)vp)[j];
      }
    }

#pragma unroll
    for (int kb = 0; kb < 2; ++kb) {
      // ---- S^T = K.Q^T with sigma-permuted A rows, both q-halves share ka ----
      f16x8_t ka[4];
#pragma unroll
      for (int kh = 0; kh < 4; ++kh)
        ka[kh] = *(const f16x8_t*)&Ks[(kb * 32 + sig) * 72 + kh * 16 + 8 * h2];
      f32x16_t s0 = {0.f,0.f,0.f,0.f,0.f,0.f,0.f,0.f,0.f,0.f,0.f,0.f,0.f,0.f,0.f,0.f};
      f32x16_t s1 = s0;
#pragma unroll
      for (int kh = 0; kh < 4; ++kh) {
        s0 = __builtin_amdgcn_mfma_f32_32x32x16_f16(ka[kh], qf[0][kh], s0, 0, 0, 0);
        s1 = __builtin_amdgcn_mfma_f32_32x32x16_f16(ka[kh], qf[1][kh], s1, 0, 0, 0);
      }

      // ---- softmax + PV: frag f = 2*kb + a uses regs 8a..8a+7, lane-local ----
#pragma unroll
      for (int a = 0; a < 2; ++a) {
        const int f = kb * 2 + a;
        const f16x8_t v0 = *(const f16x8_t*)&Vt[n * 72 + f * 16 + 8 * h2];
        const f16x8_t v1 = *(const f16x8_t*)&Vt[(32 + n) * 72 + f * 16 + 8 * h2];
#pragma unroll
        for (int qh = 0; qh < 2; ++qh) {
          union { _Float16 h[8]; f16x8_t v; f16x2_t p2[4]; } F;
          f32x4_t m0, m1;
          if (has_mask) {
            const float* mp = Mg + (size_t)(qb + qh * 32 + n) * 4096 + kbase + kb * 32 + 16 * a + 8 * h2;
            m0 = *(const f32x4_t*)(mp);
            m1 = *(const f32x4_t*)(mp + 4);
          }
#pragma unroll
          for (int idx = 0; idx < 8; ++idx) {
            float x = (qh == 0) ? s0[8 * a + idx] : s1[8 * a + idx];
            if (has_mask) {
              float m = (idx < 4) ? m0[idx] : m1[idx - 4];
              x = __builtin_fmaf(m, LOG2E, x);
            }
            F.h[idx] = (_Float16)EXP2F(x);
          }
          float* lp = (qh == 0) ? &lacc0 : &lacc1;
#pragma unroll
          for (int u = 0; u < 4; ++u) *lp = rowsum2(F.p2[u], *lp);
          if (qh == 0) {
            o00 = __builtin_amdgcn_mfma_f32_32x32x16_f16(F.v, v0, o00, 0, 0, 0);
            o01 = __builtin_amdgcn_mfma_f32_32x32x16_f16(F.v, v1, o01, 0, 0, 0);
          } else {
            o10 = __builtin_amdgcn_mfma_f32_32x32x16_f16(F.v, v0, o10, 0, 0, 0);
            o11 = __builtin_amdgcn_mfma_f32_32x32x16_f16(F.v, v1, o11, 0, 0, 0);
          }
        }
      }
    }
  }

  // ---- epilogue: l per q-column, normalize, store ----
  float* op = Og + hoff;
#pragma unroll
  for (int qh = 0; qh < 2; ++qh) {
    float la = (qh == 0) ? lacc0 : lacc1;
    float lq = la + __shfl_xor(la, 32);
#pragma unroll
    for (int r2 = 0; r2 < 4; ++r2) {
#pragma unroll
      for (int rr = 0; rr < 4; ++rr) {
        const int reg  = r2 * 4 + rr;
        const int qrow = rr + 8 * r2 + 4 * h2;      // C/D row mapping (m74/m101)
        float lr  = __shfl(lq, qrow);
        float inv = 1.0f / lr;
        const size_t row = (size_t)(qb + qh * 32 + qrow) * 64;
        if (qh == 0) {
          op[row + n]      = o00[reg] * inv;
          op[row + 32 + n] = o01[reg] * inv;
        } else {
          op[row + n]      = o10[reg] * inv;
          op[row + 32 + n] = o11[reg] * inv;
        }
      }
    }
  }
}

// ---------------- fallback (ws too small): round-3 structure, in-kernel converts ----
__launch_bounds__(256, 2)
__global__ void sdpa_kernel_fb(const float* __restrict__ Qg, const float* __restrict__ Kg,
                               const float* __restrict__ Vg, const float* __restrict__ Mg,
                               float* __restrict__ Og, const int* __restrict__ flag) {
  __shared__ __align__(16) _Float16 Ks[64 * 72];
  __shared__ __align__(16) _Float16 Vt[64 * 72];

  const int tid  = threadIdx.x;
  const int bid  = blockIdx.x;
  const int hh   = ((bid & 7) << 1) | ((bid >> 3) & 1);
  const int qt   = bid >> 4;
  const int w    = tid >> 6;
  const int lane = tid & 63;
  const int n    = lane & 31;
  const int h2   = lane >> 5;
  const int sig  = (n & 0x13) | ((n >> 1) & 4) | ((n << 1) & 8);
  const bool has_mask = (*flag) != 0;

  const size_t hoff = (size_t)hh * 4096 * 64;
  const int qcol = qt * 128 + w * 32 + n;

  f16x8_t qf[4];
  {
    const float* qp = Qg + hoff + (size_t)qcol * 64 + 8 * h2;
#pragma unroll
    for (int kh = 0; kh < 4; ++kh) {
      f32x4_t a = *(const f32x4_t*)(qp + kh * 16);
      f32x4_t b = *(const f32x4_t*)(qp + kh * 16 + 4);
      union { _Float16 h[8]; f16x8_t v; } U;
#pragma unroll
      for (int j = 0; j < 4; ++j) { U.h[j] = (_Float16)(a[j] * QSCALE); U.h[4 + j] = (_Float16)(b[j] * QSCALE); }
      qf[kh] = U.v;
    }
  }

  f32x16_t o0 = {0.f,0.f,0.f,0.f,0.f,0.f,0.f,0.f,0.f,0.f,0.f,0.f,0.f,0.f,0.f,0.f};
  f32x16_t o1 = o0;
  float lacc = 0.0f;

#pragma unroll 1
  for (int kt = 0; kt < 64; ++kt) {
    const int kbase = kt * 64;
    const float* kp = Kg + hoff + (size_t)(kbase + (tid >> 2)) * 64 + (tid & 3) * 16;
    f32x4_t k0 = *(const f32x4_t*)(kp + 0);
    f32x4_t k1 = *(const f32x4_t*)(kp + 4);
    f32x4_t k2 = *(const f32x4_t*)(kp + 8);
    f32x4_t k3 = *(const f32x4_t*)(kp + 12);
    const float* vp = Vg + hoff + (size_t)(kbase + (tid >> 5) * 8) * 64 + (tid & 31);
    float vlo[8], vhi[8];
#pragma unroll
    for (int j = 0; j < 8; ++j) { vlo[j] = vp[(size_t)j * 64]; vhi[j] = vp[(size_t)j * 64 + 32]; }

    f32x4_t mk[2][2][2];
    if (has_mask) {
      const float* mp = Mg + (size_t)qcol * 4096 + kbase + 8 * h2;
#pragma unroll
      for (int kb = 0; kb < 2; ++kb)
#pragma unroll
        for (int a = 0; a < 2; ++a)
#pragma unroll
          for (int b = 0; b < 2; ++b)
            mk[kb][a][b] = *(const f32x4_t*)(mp + kb * 32 + 16 * a + 4 * b);
    }

    __syncthreads();
    {
      union { _Float16 h[8]; uint4 q; } A, B;
#pragma unroll
      for (int j = 0; j < 4; ++j) {
        A.h[j] = (_Float16)k0[j];  A.h[4 + j] = (_Float16)k1[j];
        B.h[j] = (_Float16)k2[j];  B.h[4 + j] = (_Float16)k3[j];
      }
      *(uint4*)&Ks[(tid >> 2) * 72 + (tid & 3) * 16]     = A.q;
      *(uint4*)&Ks[(tid >> 2) * 72 + (tid & 3) * 16 + 8] = B.q;
      union { _Float16 h[8]; uint4 q; } C, D;
#pragma unroll
      for (int j = 0; j < 8; ++j) { C.h[j] = (_Float16)vlo[j]; D.h[j] = (_Float16)vhi[j]; }
      *(uint4*)&Vt[(tid & 31) * 72 + (tid >> 5) * 8]        = C.q;
      *(uint4*)&Vt[((tid & 31) + 32) * 72 + (tid >> 5) * 8] = D.q;
    }
    __syncthreads();

#pragma unroll
    for (int kb = 0; kb < 2; ++kb) {
      f32x16_t acc = {0.f,0.f,0.f,0.f,0.f,0.f,0.f,0.f,0.f,0.f,0.f,0.f,0.f,0.f,0.f,0.f};
#pragma unroll
      for (int kh = 0; kh < 4; ++kh) {
        const f16x8_t ka = *(const f16x8_t*)&Ks[(kb * 32 + sig) * 72 + kh * 16 + 8 * h2];
        acc = __builtin_amdgcn_mfma_f32_32x32x16_f16(ka, qf[kh], acc, 0, 0, 0);
      }
#pragma unroll
      for (int a = 0; a < 2; ++a) {
        union { _Float16 h[8]; f16x8_t v; f16x2_t p2[4]; } F;
#pragma unroll
        for (int idx = 0; idx < 8; ++idx) {
          float x = acc[8 * a + idx];
          if (has_mask) x = __builtin_fmaf(mk[kb][a][idx >> 2][idx & 3], LOG2E, x);
          F.h[idx] = (_Float16)EXP2F(x);
        }
#pragma unroll
        for (int u = 0; u < 4; ++u) lacc = rowsum2(F.p2[u], lacc);
        const int f = kb * 2 + a;
        const f16x8_t v0 = *(const f16x8_t*)&Vt[n * 72 + f * 16 + 8 * h2];
        o0 = __builtin_amdgcn_mfma_f32_32x32x16_f16(F.v, v0, o0, 0, 0, 0);
        const f16x8_t v1 = *(const f16x8_t*)&Vt[(32 + n) * 72 + f * 16 + 8 * h2];
        o1 = __builtin_amdgcn_mfma_f32_32x32x16_f16(F.v, v1, o1, 0, 0, 0);
      }
    }
  }

  float lq = lacc + __shfl_xor(lacc, 32);
  float* op = Og + hoff;
#pragma unroll
  for (int r2 = 0; r2 < 4; ++r2) {
#pragma unroll
    for (int rr = 0; rr < 4; ++rr) {
      const int reg  = r2 * 4 + rr;
      const int qrow = rr + 8 * r2 + 4 * h2;
      float lr  = __shfl(lq, qrow);
      float inv = 1.0f / lr;
      const size_t row = (size_t)(qt * 128 + w * 32 + qrow) * 64;
      op[row + n]      = o0[reg] * inv;
      op[row + 32 + n] = o1[reg] * inv;
    }
  }
}

extern "C" void kernel_launch(void* const* d_in, const int* in_sizes, int n_in,
                              void* d_out, int out_size, void* d_ws, size_t ws_size,
                              hipStream_t stream) {
  const float* Q = (const float*)d_in[0];
  const float* K = (const float*)d_in[1];
  const float* V = (const float*)d_in[2];
  const float* M = (const float*)d_in[3];
  float* O = (float*)d_out;

  const size_t NELEM = (size_t)16 * 4096 * 64;
  const size_t need  = 256 + 3 * NELEM * sizeof(_Float16);
  int* flag = (int*)d_ws;

  hipMemsetAsync(flag, 0, sizeof(int), stream);
  mask_scan_kernel<<<2048, 256, 0, stream>>>(M, flag);

  if (ws_size >= need) {
    _Float16* Qh  = (_Float16*)((char*)d_ws + 256);
    _Float16* Kh  = Qh + NELEM;
    _Float16* Vth = Kh + NELEM;
    convert_qk_kernel<<<2048, 256, 0, stream>>>(Q, K, Qh, Kh);
    transpose_v_kernel<<<1024, 256, 0, stream>>>(V, Vth);
    sdpa_kernel2<<<512, 128, 0, stream>>>(Qh, Kh, Vth, M, O, flag);
  } else {
    sdpa_kernel_fb<<<512, 256, 0, stream>>>(Q, K, V, M, O, flag);
  }
}

// Round 5
// 317.120 us; speedup vs baseline: 1.0502x; 1.0502x over previous
//
#include <hip/hip_runtime.h>
#include <stdint.h>

#define LOG2E  1.44269504088896f
#define QSCALE (0.125f * LOG2E)   // folded into Q: sacc is already the exp2 argument

typedef float    f32x4_t  __attribute__((ext_vector_type(4)));
typedef float    f32x16_t __attribute__((ext_vector_type(16)));
typedef _Float16 f16x8_t  __attribute__((ext_vector_type(8)));
typedef _Float16 f16x2_t  __attribute__((ext_vector_type(2)));

#if __has_builtin(__builtin_amdgcn_exp2f)
#define EXP2F(x) __builtin_amdgcn_exp2f(x)
#else
#define EXP2F(x) exp2f(x)
#endif

__device__ __forceinline__ float rowsum2(f16x2_t p, float acc) {
#if __has_builtin(__builtin_amdgcn_fdot2)
  return __builtin_amdgcn_fdot2(p, (f16x2_t){(_Float16)1.0f, (_Float16)1.0f}, acc, false);
#else
  return acc + (float)p[0] + (float)p[1];
#endif
}

// ---------------- mask all-zero scan ----------------
__global__ void mask_scan_kernel(const float* __restrict__ m, int* __restrict__ flag) {
  const float* p = m + (size_t)blockIdx.x * 8192 + (size_t)threadIdx.x * 4;
  unsigned acc = 0;
#pragma unroll
  for (int i = 0; i < 8; ++i) {
    f32x4_t v = *(const f32x4_t*)(p + (size_t)i * 1024);
    acc |= __float_as_uint(v[0]) | __float_as_uint(v[1]) |
           __float_as_uint(v[2]) | __float_as_uint(v[3]);
  }
  acc &= 0x7fffffffu;
  if (acc) atomicOr(flag, 1);
}

// ---------------- pre-convert Q (scaled) and K to fp16 ----------------
__global__ void convert_qk_kernel(const float* __restrict__ Q, const float* __restrict__ K,
                                  _Float16* __restrict__ Qh, _Float16* __restrict__ Kh) {
  const size_t idx = ((size_t)blockIdx.x * 256 + threadIdx.x) * 8;
  {
    f32x4_t a = *(const f32x4_t*)(Q + idx);
    f32x4_t b = *(const f32x4_t*)(Q + idx + 4);
    union { _Float16 h[8]; uint4 q; } U;
#pragma unroll
    for (int j = 0; j < 4; ++j) { U.h[j] = (_Float16)(a[j] * QSCALE); U.h[4 + j] = (_Float16)(b[j] * QSCALE); }
    *(uint4*)(Qh + idx) = U.q;
  }
  {
    f32x4_t a = *(const f32x4_t*)(K + idx);
    f32x4_t b = *(const f32x4_t*)(K + idx + 4);
    union { _Float16 h[8]; uint4 q; } U;
#pragma unroll
    for (int j = 0; j < 4; ++j) { U.h[j] = (_Float16)a[j]; U.h[4 + j] = (_Float16)b[j]; }
    *(uint4*)(Kh + idx) = U.q;
  }
}

// ---------------- pre-transpose V to fp16 [head][feat][seq] ----------------
__global__ void transpose_v_kernel(const float* __restrict__ V, _Float16* __restrict__ Vth) {
  __shared__ __align__(16) _Float16 T[64 * 72];
  const int tid  = threadIdx.x;
  const int head = blockIdx.x >> 6;
  const int st   = blockIdx.x & 63;
  const size_t hoff = (size_t)head * 4096 * 64;

  const int sl    = tid >> 2;
  const int fbase = (tid & 3) * 16;
  const float* src = V + hoff + (size_t)(st * 64 + sl) * 64 + fbase;
#pragma unroll
  for (int c = 0; c < 4; ++c) {
    f32x4_t a = *(const f32x4_t*)(src + c * 4);
#pragma unroll
    for (int j = 0; j < 4; ++j) T[(fbase + c * 4 + j) * 72 + sl] = (_Float16)a[j];
  }
  __syncthreads();
  const int feat = tid >> 2;
  const int sb   = (tid & 3) * 16;
  uint4 r0 = *(const uint4*)&T[feat * 72 + sb];
  uint4 r1 = *(const uint4*)&T[feat * 72 + sb + 8];
  _Float16* dst = Vth + hoff + (size_t)feat * 4096 + st * 64 + sb;
  *(uint4*)(dst)     = r0;
  *(uint4*)(dst + 8) = r1;
}

// ---------------- SDPA core v3: 256 thr (4 waves), 64 q/wave, key-parity split ----
// wave w: q-half (w&1), key-tile parity (w>>1). Each round stages 128 keys into
// two 64-key LDS buffers; partial O/l of the two parities combined via LDS at end
// (exp softmax has no running max -> partials are additive).
// sigma trick: K rows read through sig(n)=swap(bit2,bit3) during S^T=K.Q^T so PV
// A-fragments are lane-local sacc regs (no P LDS round-trip).
__launch_bounds__(256, 2)
__global__ void sdpa_kernel3(const _Float16* __restrict__ Qh, const _Float16* __restrict__ Kh,
                             const _Float16* __restrict__ Vth, const float* __restrict__ Mg,
                             float* __restrict__ Og, const int* __restrict__ flag) {
  __shared__ __align__(16) char smem[36864];
  _Float16* Ks = (_Float16*)smem;              // [2][64*72]  [key][feat]
  _Float16* Vt = (_Float16*)(smem + 18432);    // [2][64*72]  [feat][key]
  float*    scr = (float*)smem;                // epilogue scratch (2*64*68 floats)

  const int t    = threadIdx.x;
  const int bid  = blockIdx.x;                           // 0..511
  const int hh   = ((bid & 7) << 1) | ((bid >> 3) & 1);  // 2 heads per XCD
  const int qt   = bid >> 4;                             // 0..31
  const int w    = t >> 6;
  const int lane = t & 63;
  const int n    = lane & 31;
  const int h2   = lane >> 5;
  const int qhw  = w & 1;                                // wave's q-half (64 q)
  const int par  = w >> 1;                               // wave's key-tile parity
  const int sig  = (n & 0x13) | ((n >> 1) & 4) | ((n << 1) & 8);  // swap bits 2,3
  const bool has_mask = (*flag) != 0;

  const size_t hoff = (size_t)hh * 4096 * 64;
  const int qb = qt * 128 + qhw * 64;                    // wave's q base

  // ---- Q B-fragments for both 32-q sub-halves ----
  f16x8_t qf[2][4];
#pragma unroll
  for (int qh = 0; qh < 2; ++qh) {
    const _Float16* qp = Qh + hoff + (size_t)(qb + qh * 32 + n) * 64 + 8 * h2;
#pragma unroll
    for (int kh = 0; kh < 4; ++kh) qf[qh][kh] = *(const f16x8_t*)(qp + kh * 16);
  }

  f32x16_t o00 = {0.f,0.f,0.f,0.f,0.f,0.f,0.f,0.f,0.f,0.f,0.f,0.f,0.f,0.f,0.f,0.f};
  f32x16_t o01 = o00, o10 = o00, o11 = o00;   // o[sub-qh][col-half]
  float lacc0 = 0.0f, lacc1 = 0.0f;

  // staging: K row sr (0..127) feat-half sh; V feat vf (0..63) key-quarter vq
  const int sr = t >> 1;
  const int sh = (t & 1) * 32;
  const int vf = t >> 2;
  const int vq = (t & 3) * 32;
  const _Float16* kgp = Kh  + hoff + (size_t)sr * 64 + sh;
  const _Float16* vgp = Vth + hoff + (size_t)vf * 4096 + vq;
  _Float16* kd = Ks + (sr >> 6) * 4608 + (sr & 63) * 72 + sh;
  _Float16* vd = Vt + (vq >> 6) * 4608 + vf * 72 + (vq & 63);

  uint4 kk[4], vv[4];
#pragma unroll
  for (int j = 0; j < 4; ++j) {               // prefetch round 0
    kk[j] = ((const uint4*)kgp)[j];
    vv[j] = ((const uint4*)vgp)[j];
  }

  const _Float16* Ksb = Ks + par * 4608;
  const _Float16* Vtb = Vt + par * 4608;

#pragma unroll 1
  for (int rd = 0; rd < 32; ++rd) {
    __syncthreads();   // prior round's LDS reads complete before overwrite
    {
      uint4* kp = (uint4*)kd;
      uint4* vp = (uint4*)vd;
#pragma unroll
      for (int j = 0; j < 4; ++j) { kp[j] = kk[j]; vp[j] = vv[j]; }
    }
    __syncthreads();   // staging visible

    if (rd < 31) {     // prefetch next round: latency hides under this round's compute
      const _Float16* kp = kgp + (size_t)(rd + 1) * 128 * 64;
      const _Float16* vp = vgp + (size_t)(rd + 1) * 128;
#pragma unroll
      for (int j = 0; j < 4; ++j) {
        kk[j] = ((const uint4*)kp)[j];
        vv[j] = ((const uint4*)vp)[j];
      }
    }

    const int kbase = rd * 128 + par * 64;    // this wave's 64 keys

#pragma unroll
    for (int kb = 0; kb < 2; ++kb) {
      f16x8_t ka[4];
#pragma unroll
      for (int kh = 0; kh < 4; ++kh)
        ka[kh] = *(const f16x8_t*)&Ksb[(kb * 32 + sig) * 72 + kh * 16 + 8 * h2];
      f32x16_t s0 = {0.f,0.f,0.f,0.f,0.f,0.f,0.f,0.f,0.f,0.f,0.f,0.f,0.f,0.f,0.f,0.f};
      f32x16_t s1 = s0;
#pragma unroll
      for (int kh = 0; kh < 4; ++kh) {
        s0 = __builtin_amdgcn_mfma_f32_32x32x16_f16(ka[kh], qf[0][kh], s0, 0, 0, 0);
        s1 = __builtin_amdgcn_mfma_f32_32x32x16_f16(ka[kh], qf[1][kh], s1, 0, 0, 0);
      }

#pragma unroll
      for (int a = 0; a < 2; ++a) {
        const int f = kb * 2 + a;
        const f16x8_t v0 = *(const f16x8_t*)&Vtb[n * 72 + f * 16 + 8 * h2];
        const f16x8_t v1 = *(const f16x8_t*)&Vtb[(32 + n) * 72 + f * 16 + 8 * h2];
#pragma unroll
        for (int qh = 0; qh < 2; ++qh) {
          union { _Float16 h[8]; f16x8_t v; f16x2_t p2[4]; } F;
          f32x4_t m0, m1;
          if (has_mask) {
            const float* mp = Mg + (size_t)(qb + qh * 32 + n) * 4096 + kbase + kb * 32 + 16 * a + 8 * h2;
            m0 = *(const f32x4_t*)(mp);
            m1 = *(const f32x4_t*)(mp + 4);
          }
#pragma unroll
          for (int idx = 0; idx < 8; ++idx) {
            float x = (qh == 0) ? s0[8 * a + idx] : s1[8 * a + idx];
            if (has_mask) {
              float m = (idx < 4) ? m0[idx] : m1[idx - 4];
              x = __builtin_fmaf(m, LOG2E, x);
            }
            F.h[idx] = (_Float16)EXP2F(x);
          }
          float* lp = (qh == 0) ? &lacc0 : &lacc1;
#pragma unroll
          for (int u = 0; u < 4; ++u) *lp = rowsum2(F.p2[u], *lp);
          if (qh == 0) {
            o00 = __builtin_amdgcn_mfma_f32_32x32x16_f16(F.v, v0, o00, 0, 0, 0);
            o01 = __builtin_amdgcn_mfma_f32_32x32x16_f16(F.v, v1, o01, 0, 0, 0);
          } else {
            o10 = __builtin_amdgcn_mfma_f32_32x32x16_f16(F.v, v0, o10, 0, 0, 0);
            o11 = __builtin_amdgcn_mfma_f32_32x32x16_f16(F.v, v1, o11, 0, 0, 0);
          }
        }
      }
    }
  }

  // ---- combine key-parity partials (additive: no max rescaling) via LDS ----
  __syncthreads();
  if (w >= 2) {
    float* dst = scr + (size_t)qhw * (64 * 68) + (size_t)lane * 68;
#pragma unroll
    for (int j = 0; j < 16; ++j) {
      dst[j]      = o00[j];
      dst[16 + j] = o01[j];
      dst[32 + j] = o10[j];
      dst[48 + j] = o11[j];
    }
    dst[64] = lacc0;
    dst[65] = lacc1;
  }
  __syncthreads();
  if (w < 2) {
    const float* src = scr + (size_t)qhw * (64 * 68) + (size_t)lane * 68;
#pragma unroll
    for (int j = 0; j < 16; ++j) {
      o00[j] += src[j];
      o01[j] += src[16 + j];
      o10[j] += src[32 + j];
      o11[j] += src[48 + j];
    }
    lacc0 += src[64];
    lacc1 += src[65];

    // ---- epilogue: l per q-column, normalize, store ----
    float* op = Og + hoff;
#pragma unroll
    for (int qh = 0; qh < 2; ++qh) {
      float la = (qh == 0) ? lacc0 : lacc1;
      float lq = la + __shfl_xor(la, 32);
#pragma unroll
      for (int r2 = 0; r2 < 4; ++r2) {
#pragma unroll
        for (int rr = 0; rr < 4; ++rr) {
          const int reg  = r2 * 4 + rr;
          const int qrow = rr + 8 * r2 + 4 * h2;      // C/D row mapping (m74/m101)
          float lr  = __shfl(lq, qrow);
          float inv = 1.0f / lr;
          const size_t row = (size_t)(qb + qh * 32 + qrow) * 64;
          if (qh == 0) {
            op[row + n]      = o00[reg] * inv;
            op[row + 32 + n] = o01[reg] * inv;
          } else {
            op[row + n]      = o10[reg] * inv;
            op[row + 32 + n] = o11[reg] * inv;
          }
        }
      }
    }
  }
}

// ---------------- fallback (ws too small): round-3 structure, in-kernel converts ----
__launch_bounds__(256, 2)
__global__ void sdpa_kernel_fb(const float* __restrict__ Qg, const float* __restrict__ Kg,
                               const float* __restrict__ Vg, const float* __restrict__ Mg,
                               float* __restrict__ Og, const int* __restrict__ flag) {
  __shared__ __align__(16) _Float16 Ks[64 * 72];
  __shared__ __align__(16) _Float16 Vt[64 * 72];

  const int tid  = threadIdx.x;
  const int bid  = blockIdx.x;
  const int hh   = ((bid & 7) << 1) | ((bid >> 3) & 1);
  const int qt   = bid >> 4;
  const int w    = tid >> 6;
  const int lane = tid & 63;
  const int n    = lane & 31;
  const int h2   = lane >> 5;
  const int sig  = (n & 0x13) | ((n >> 1) & 4) | ((n << 1) & 8);
  const bool has_mask = (*flag) != 0;

  const size_t hoff = (size_t)hh * 4096 * 64;
  const int qcol = qt * 128 + w * 32 + n;

  f16x8_t qf[4];
  {
    const float* qp = Qg + hoff + (size_t)qcol * 64 + 8 * h2;
#pragma unroll
    for (int kh = 0; kh < 4; ++kh) {
      f32x4_t a = *(const f32x4_t*)(qp + kh * 16);
      f32x4_t b = *(const f32x4_t*)(qp + kh * 16 + 4);
      union { _Float16 h[8]; f16x8_t v; } U;
#pragma unroll
      for (int j = 0; j < 4; ++j) { U.h[j] = (_Float16)(a[j] * QSCALE); U.h[4 + j] = (_Float16)(b[j] * QSCALE); }
      qf[kh] = U.v;
    }
  }

  f32x16_t o0 = {0.f,0.f,0.f,0.f,0.f,0.f,0.f,0.f,0.f,0.f,0.f,0.f,0.f,0.f,0.f,0.f};
  f32x16_t o1 = o0;
  float lacc = 0.0f;

#pragma unroll 1
  for (int kt = 0; kt < 64; ++kt) {
    const int kbase = kt * 64;
    const float* kp = Kg + hoff + (size_t)(kbase + (tid >> 2)) * 64 + (tid & 3) * 16;
    f32x4_t k0 = *(const f32x4_t*)(kp + 0);
    f32x4_t k1 = *(const f32x4_t*)(kp + 4);
    f32x4_t k2 = *(const f32x4_t*)(kp + 8);
    f32x4_t k3 = *(const f32x4_t*)(kp + 12);
    const float* vp = Vg + hoff + (size_t)(kbase + (tid >> 5) * 8) * 64 + (tid & 31);
    float vlo[8], vhi[8];
#pragma unroll
    for (int j = 0; j < 8; ++j) { vlo[j] = vp[(size_t)j * 64]; vhi[j] = vp[(size_t)j * 64 + 32]; }

    f32x4_t mk[2][2][2];
    if (has_mask) {
      const float* mp = Mg + (size_t)qcol * 4096 + kbase + 8 * h2;
#pragma unroll
      for (int kb = 0; kb < 2; ++kb)
#pragma unroll
        for (int a = 0; a < 2; ++a)
#pragma unroll
          for (int b = 0; b < 2; ++b)
            mk[kb][a][b] = *(const f32x4_t*)(mp + kb * 32 + 16 * a + 4 * b);
    }

    __syncthreads();
    {
      union { _Float16 h[8]; uint4 q; } A, B;
#pragma unroll
      for (int j = 0; j < 4; ++j) {
        A.h[j] = (_Float16)k0[j];  A.h[4 + j] = (_Float16)k1[j];
        B.h[j] = (_Float16)k2[j];  B.h[4 + j] = (_Float16)k3[j];
      }
      *(uint4*)&Ks[(tid >> 2) * 72 + (tid & 3) * 16]     = A.q;
      *(uint4*)&Ks[(tid >> 2) * 72 + (tid & 3) * 16 + 8] = B.q;
      union { _Float16 h[8]; uint4 q; } C, D;
#pragma unroll
      for (int j = 0; j < 8; ++j) { C.h[j] = (_Float16)vlo[j]; D.h[j] = (_Float16)vhi[j]; }
      *(uint4*)&Vt[(tid & 31) * 72 + (tid >> 5) * 8]        = C.q;
      *(uint4*)&Vt[((tid & 31) + 32) * 72 + (tid >> 5) * 8] = D.q;
    }
    __syncthreads();

#pragma unroll
    for (int kb = 0; kb < 2; ++kb) {
      f32x16_t acc = {0.f,0.f,0.f,0.f,0.f,0.f,0.f,0.f,0.f,0.f,0.f,0.f,0.f,0.f,0.f,0.f};
#pragma unroll
      for (int kh = 0; kh < 4; ++kh) {
        const f16x8_t ka = *(const f16x8_t*)&Ks[(kb * 32 + sig) * 72 + kh * 16 + 8 * h2];
        acc = __builtin_amdgcn_mfma_f32_32x32x16_f16(ka, qf[kh], acc, 0, 0, 0);
      }
#pragma unroll
      for (int a = 0; a < 2; ++a) {
        union { _Float16 h[8]; f16x8_t v; f16x2_t p2[4]; } F;
#pragma unroll
        for (int idx = 0; idx < 8; ++idx) {
          float x = acc[8 * a + idx];
          if (has_mask) x = __builtin_fmaf(mk[kb][a][idx >> 2][idx & 3], LOG2E, x);
          F.h[idx] = (_Float16)EXP2F(x);
        }
#pragma unroll
        for (int u = 0; u < 4; ++u) lacc = rowsum2(F.p2[u], lacc);
        const int f = kb * 2 + a;
        const f16x8_t v0 = *(const f16x8_t*)&Vt[n * 72 + f * 16 + 8 * h2];
        o0 = __builtin_amdgcn_mfma_f32_32x32x16_f16(F.v, v0, o0, 0, 0, 0);
        const f16x8_t v1 = *(const f16x8_t*)&Vt[(32 + n) * 72 + f * 16 + 8 * h2];
        o1 = __builtin_amdgcn_mfma_f32_32x32x16_f16(F.v, v1, o1, 0, 0, 0);
      }
    }
  }

  float lq = lacc + __shfl_xor(lacc, 32);
  float* op = Og + hoff;
#pragma unroll
  for (int r2 = 0; r2 < 4; ++r2) {
#pragma unroll
    for (int rr = 0; rr < 4; ++rr) {
      const int reg  = r2 * 4 + rr;
      const int qrow = rr + 8 * r2 + 4 * h2;
      float lr  = __shfl(lq, qrow);
      float inv = 1.0f / lr;
      const size_t row = (size_t)(qt * 128 + w * 32 + qrow) * 64;
      op[row + n]      = o0[reg] * inv;
      op[row + 32 + n] = o1[reg] * inv;
    }
  }
}

extern "C" void kernel_launch(void* const* d_in, const int* in_sizes, int n_in,
                              void* d_out, int out_size, void* d_ws, size_t ws_size,
                              hipStream_t stream) {
  const float* Q = (const float*)d_in[0];
  const float* K = (const float*)d_in[1];
  const float* V = (const float*)d_in[2];
  const float* M = (const float*)d_in[3];
  float* O = (float*)d_out;

  const size_t NELEM = (size_t)16 * 4096 * 64;
  const size_t need  = 256 + 3 * NELEM * sizeof(_Float16);
  int* flag = (int*)d_ws;

  hipMemsetAsync(flag, 0, sizeof(int), stream);
  mask_scan_kernel<<<2048, 256, 0, stream>>>(M, flag);

  if (ws_size >= need) {
    _Float16* Qh  = (_Float16*)((char*)d_ws + 256);
    _Float16* Kh  = Qh + NELEM;
    _Float16* Vth = Kh + NELEM;
    convert_qk_kernel<<<2048, 256, 0, stream>>>(Q, K, Qh, Kh);
    transpose_v_kernel<<<1024, 256, 0, stream>>>(V, Vth);
    sdpa_kernel3<<<512, 256, 0, stream>>>(Qh, Kh, Vth, M, O, flag);
  } else {
    sdpa_kernel_fb<<<512, 256, 0, stream>>>(Q, K, V, M, O, flag);
  }
}